// Round 1
// baseline (130.136 us; speedup 1.0000x reference)
//
#include <hip/hip_runtime.h>
#include <math.h>

#define NPTS 8192
#define NB   128
#define EPS  1.1920929e-07f

__device__ __forceinline__ float rdlane(float v, int l) {
    return __int_as_float(__builtin_amdgcn_readlane(__float_as_int(v), l));
}

// ---------------------------------------------------------------------------
// K1: per-ball prep:  a = rmsnorm(x)*n1w + (pos - ball_mean(pos))
//     writes A2[b][h][m][e]  (ball-head-major, each (b,h) slice contiguous 2KB)
//     writes bmT[d][b] = ball-mean of a  (routing keys, transposed)
//     blocks >= NB transpose the MLP weights.
// ---------------------------------------------------------------------------
__global__ __launch_bounds__(256) void k_prep(
    const float* __restrict__ x, const float* __restrict__ pos,
    const float* __restrict__ n1w,
    const float* __restrict__ w1, const float* __restrict__ w2,
    const float* __restrict__ w3,
    float* __restrict__ A2, float* __restrict__ bmT,
    float* __restrict__ w1T, float* __restrict__ w2T, float* __restrict__ w3T)
{
    int t = threadIdx.x;
    int blk = blockIdx.x;
    if (blk >= NB) {
        int base = (blk - NB) * 1024 + t * 4;
        #pragma unroll
        for (int c = 0; c < 4; ++c) {
            int idx = base + c;
            if (idx < 16384) {
                int e = idx >> 8, k = idx & 255;
                w1T[idx] = w1[k * 64 + e];
            } else if (idx < 32768) {
                int o = idx - 16384; int e = o >> 8, k = o & 255;
                w2T[o] = w2[k * 64 + e];
            } else {
                int o = idx - 32768; int k = o >> 6, d = o & 63;
                w3T[o] = w3[d * 256 + k];
            }
        }
        return;
    }
    __shared__ float xs[64 * 68];     // x ball, later holds a in-place
    __shared__ float ps[64 * 68];     // pos ball
    __shared__ float red[256], red2[256];
    __shared__ float pm[64], rs[64], nw[64];

    const float* xb = x + blk * 4096;
    const float* pb = pos + blk * 4096;
    if (t < 64) nw[t] = n1w[t];
    #pragma unroll
    for (int it = 0; it < 4; ++it) {
        int o4 = t + it * 256;                 // float4 index 0..1023
        int row = o4 >> 4, col = (o4 & 15) * 4;
        float4 xv = ((const float4*)xb)[o4];
        float4 pv = ((const float4*)pb)[o4];
        *(float4*)&xs[row * 68 + col] = xv;    // (row*68+col)*4 is 16B aligned
        *(float4*)&ps[row * 68 + col] = pv;
    }
    __syncthreads();
    {   // pos column partials (mg,d) and x row-sumsq partials (m,q)
        int mg = t >> 6, d = t & 63;
        float s = 0.f;
        #pragma unroll
        for (int p = 0; p < 16; ++p) s += ps[(mg * 16 + p) * 68 + d];
        red[t] = s;
        int m = t >> 2, q = t & 3;
        float ss = 0.f;
        #pragma unroll
        for (int j = 0; j < 16; ++j) { float v = xs[m * 68 + q * 16 + j]; ss += v * v; }
        red2[t] = ss;
    }
    __syncthreads();
    if (t < 64) {
        pm[t] = (red[t] + red[t + 64] + red[t + 128] + red[t + 192]) * (1.0f / 64.0f);
        float s = red2[t * 4] + red2[t * 4 + 1] + red2[t * 4 + 2] + red2[t * 4 + 3];
        rs[t] = 1.0f / sqrtf(s * (1.0f / 64.0f) + EPS);
    }
    __syncthreads();
    {   // a = xn*scale*w + (pos - pm), in place into xs
        int m = t >> 2, q = t & 3;
        float sc = rs[m];
        #pragma unroll
        for (int j = 0; j < 16; ++j) {
            int d = q * 16 + j;
            int a = m * 68 + d;
            xs[a] = xs[a] * sc * nw[d] + (ps[a] - pm[d]);
        }
    }
    __syncthreads();
    {   // column sums of a (for routing keys) + coalesced A2 write
        int mg = t >> 6, d = t & 63;
        float s = 0.f;
        #pragma unroll
        for (int p = 0; p < 16; ++p) s += xs[(mg * 16 + p) * 68 + d];
        red[t] = s;
        float* a2b = A2 + blk * 4096;
        #pragma unroll
        for (int it = 0; it < 16; ++it) {
            int o = t + it * 256;              // o = h*512 + m*8 + e
            int e = o & 7, m = (o >> 3) & 63, hh = o >> 9;
            a2b[o] = xs[m * 68 + hh * 8 + e];
        }
    }
    __syncthreads();
    if (t < 64) {
        float s = red[t] + red[t + 64] + red[t + 128] + red[t + 192];
        bmT[t * 128 + blk] = s * (1.0f / 64.0f);
    }
}

// ---------------------------------------------------------------------------
// K2: routing (top-2 balls, exact jax tie semantics) + attention + residual.
// 16 lanes per (point,head) task; 4 tasks/wave; all tasks in a block share h.
// No LDS, no barriers.
// ---------------------------------------------------------------------------
__global__ __launch_bounds__(256) void k_attn(
    const float* __restrict__ x, const float* __restrict__ A2,
    const float* __restrict__ bmT, float* __restrict__ hws)
{
    int h = blockIdx.x >> 9;                       // 512 blocks per head
    int i = ((blockIdx.x & 511) << 4) + (threadIdx.x >> 4);
    int lane = threadIdx.x & 15;
    int bi = i >> 6, mi = i & 63;

    const float* qp = A2 + ((bi * 8 + h) * 64 + mi) * 8;
    float q[8];
    #pragma unroll
    for (int e = 0; e < 8; ++e) q[e] = qp[e];

    // ---- routing: top-2 over 128 ball-mean keys ----
    const float* bmh = bmT + h * 1024;             // [e][b] slice, 4KB, L1-hot
    float bv0 = -3.4e38f, bv1 = -3.4e38f;
    int ix0 = 0, ix1 = 0;
    #pragma unroll
    for (int j = 0; j < 8; ++j) {
        int b = lane + j * 16;                     // strictly increasing per lane
        float lg = 0.f;
        #pragma unroll
        for (int e = 0; e < 8; ++e) lg = fmaf(q[e], bmh[e * 128 + b], lg);
        if (lg > bv0)      { bv1 = bv0; ix1 = ix0; bv0 = lg; ix0 = b; }
        else if (lg > bv1) { bv1 = lg; ix1 = b; }
    }
    #pragma unroll
    for (int st = 1; st < 16; st <<= 1) {
        float ov0 = __shfl_xor(bv0, st); int oi0 = __shfl_xor(ix0, st);
        float ov1 = __shfl_xor(bv1, st); int oi1 = __shfl_xor(ix1, st);
        bool aw = (bv0 > ov0) || (bv0 == ov0 && ix0 < oi0);
        if (aw) {
            if ((ov0 > bv1) || (ov0 == bv1 && oi0 < ix1)) { bv1 = ov0; ix1 = oi0; }
        } else {
            if ((bv0 > ov1) || (bv0 == ov1 && ix0 < oi1)) { bv1 = bv0; ix1 = ix0; }
            else                                          { bv1 = ov1; ix1 = oi1; }
            bv0 = ov0; ix0 = oi0;
        }
    }

    // ---- attention over the 2 selected balls (gates == 1.0 exactly) ----
    const float* k0 = A2 + (ix0 * 8 + h) * 512;    // contiguous 2KB slices
    const float* k1 = A2 + (ix1 * 8 + h) * 512;
    const float SC = 0.35355339059327373f;         // EH^-0.5
    float s0[4], s1[4];
    float mx = -3.4e38f;
    #pragma unroll
    for (int jj = 0; jj < 4; ++jj) {
        int m = lane + jj * 16;
        float4 ra = ((const float4*)(k0 + m * 8))[0];
        float4 rb = ((const float4*)(k0 + m * 8))[1];
        float d0 = q[0]*ra.x + q[1]*ra.y + q[2]*ra.z + q[3]*ra.w
                 + q[4]*rb.x + q[5]*rb.y + q[6]*rb.z + q[7]*rb.w;
        s0[jj] = d0 * SC;
        float4 rc = ((const float4*)(k1 + m * 8))[0];
        float4 rd = ((const float4*)(k1 + m * 8))[1];
        float d1 = q[0]*rc.x + q[1]*rc.y + q[2]*rc.z + q[3]*rc.w
                 + q[4]*rd.x + q[5]*rd.y + q[6]*rd.z + q[7]*rd.w;
        s1[jj] = d1 * SC;
        mx = fmaxf(mx, fmaxf(s0[jj], s1[jj]));
    }
    #pragma unroll
    for (int st = 1; st < 16; st <<= 1) mx = fmaxf(mx, __shfl_xor(mx, st));
    float sum = 0.f;
    #pragma unroll
    for (int jj = 0; jj < 4; ++jj) {
        s0[jj] = expf(s0[jj] - mx); sum += s0[jj];
        s1[jj] = expf(s1[jj] - mx); sum += s1[jj];
    }
    #pragma unroll
    for (int st = 1; st < 16; st <<= 1) sum += __shfl_xor(sum, st);
    float inv = 1.0f / sum;

    float acc[8] = {0,0,0,0,0,0,0,0};
    #pragma unroll
    for (int jj = 0; jj < 4; ++jj) {
        int m = lane + jj * 16;
        float4 ra = ((const float4*)(k0 + m * 8))[0];
        float4 rb = ((const float4*)(k0 + m * 8))[1];
        float p = s0[jj] * inv;
        acc[0] += p*ra.x; acc[1] += p*ra.y; acc[2] += p*ra.z; acc[3] += p*ra.w;
        acc[4] += p*rb.x; acc[5] += p*rb.y; acc[6] += p*rb.z; acc[7] += p*rb.w;
        float4 rc = ((const float4*)(k1 + m * 8))[0];
        float4 rd = ((const float4*)(k1 + m * 8))[1];
        float p2 = s1[jj] * inv;
        acc[0] += p2*rc.x; acc[1] += p2*rc.y; acc[2] += p2*rc.z; acc[3] += p2*rc.w;
        acc[4] += p2*rd.x; acc[5] += p2*rd.y; acc[6] += p2*rd.z; acc[7] += p2*rd.w;
    }
    #pragma unroll
    for (int st = 1; st < 16; st <<= 1) {
        #pragma unroll
        for (int e = 0; e < 8; ++e) acc[e] += __shfl_xor(acc[e], st);
    }
    if (lane < 8) {
        float v = acc[0];
        #pragma unroll
        for (int e = 1; e < 8; ++e) if (lane == e) v = acc[e];
        int off = i * 64 + h * 8 + lane;
        hws[off] = x[off] + v;                     // residual with ORIGINAL x
    }
}

// ---------------------------------------------------------------------------
// K3: rmsnorm + SwiGLU MLP + residual. One wave per 8 rows; LDS-free;
// activation broadcast via v_readlane (all register indices compile-time).
// ---------------------------------------------------------------------------
__global__ __launch_bounds__(256) void k_mlp(
    const float* __restrict__ hws, const float* __restrict__ n2w,
    const float* __restrict__ w1T, const float* __restrict__ b1,
    const float* __restrict__ w2T, const float* __restrict__ b2,
    const float* __restrict__ w3T, const float* __restrict__ b3,
    float* __restrict__ out)
{
    int lane = threadIdx.x & 63;
    int wv = blockIdx.x * 4 + (threadIdx.x >> 6);
    int r0 = wv * 8;

    float hreg[8], hn[8];
    float nw = n2w[lane];
    #pragma unroll
    for (int r = 0; r < 8; ++r) hreg[r] = hws[(r0 + r) * 64 + lane];
    #pragma unroll
    for (int r = 0; r < 8; ++r) {
        float s = hreg[r] * hreg[r];
        #pragma unroll
        for (int st = 1; st < 64; st <<= 1) s += __shfl_xor(s, st);
        float sc = 1.0f / sqrtf(s * (1.0f / 64.0f) + EPS);
        hn[r] = hreg[r] * sc * nw;
    }

    float a1[32], a2[32];
    #pragma unroll
    for (int z = 0; z < 32; ++z) { a1[z] = 0.f; a2[z] = 0.f; }
    #pragma unroll 4
    for (int e = 0; e < 64; ++e) {
        float w1v[4], w2v[4];
        #pragma unroll
        for (int u = 0; u < 4; ++u) {
            w1v[u] = w1T[e * 256 + u * 64 + lane];
            w2v[u] = w2T[e * 256 + u * 64 + lane];
        }
        #pragma unroll
        for (int r = 0; r < 8; ++r) {
            float hb = rdlane(hn[r], e);
            #pragma unroll
            for (int u = 0; u < 4; ++u) {
                a1[u * 8 + r] = fmaf(hb, w1v[u], a1[u * 8 + r]);
                a2[u * 8 + r] = fmaf(hb, w2v[u], a2[u * 8 + r]);
            }
        }
    }

    float hid[32];
    #pragma unroll
    for (int u = 0; u < 4; ++u) {
        float bb1 = b1[u * 64 + lane], bb2 = b2[u * 64 + lane];
        #pragma unroll
        for (int r = 0; r < 8; ++r) {
            float z = a1[u * 8 + r] + bb1;
            float g = z / (1.0f + expf(-z));       // silu
            hid[u * 8 + r] = (a2[u * 8 + r] + bb2) * g;
        }
    }

    float acc[8] = {0,0,0,0,0,0,0,0};
    #pragma unroll
    for (int u = 0; u < 4; ++u) {
        #pragma unroll 8
        for (int kl = 0; kl < 64; ++kl) {
            float w3v = w3T[(u * 64 + kl) * 64 + lane];
            #pragma unroll
            for (int r = 0; r < 8; ++r)
                acc[r] = fmaf(rdlane(hid[u * 8 + r], kl), w3v, acc[r]);
        }
    }
    float b3v = b3[lane];
    #pragma unroll
    for (int r = 0; r < 8; ++r)
        out[(r0 + r) * 64 + lane] = hreg[r] + acc[r] + b3v;
}

// ---------------------------------------------------------------------------
extern "C" void kernel_launch(void* const* d_in, const int* in_sizes, int n_in,
                              void* d_out, int out_size, void* d_ws, size_t ws_size,
                              hipStream_t stream)
{
    const float* x   = (const float*)d_in[0];
    const float* pos = (const float*)d_in[1];
    const float* n1w = (const float*)d_in[2];
    const float* n2w = (const float*)d_in[3];
    const float* w1  = (const float*)d_in[4];
    const float* b1  = (const float*)d_in[5];
    const float* w2  = (const float*)d_in[6];
    const float* b2  = (const float*)d_in[7];
    const float* w3  = (const float*)d_in[8];
    const float* b3  = (const float*)d_in[9];
    float* outp = (float*)d_out;
    float* ws = (float*)d_ws;

    float* A2  = ws;                 // 524288 floats: a in [b][h][m][e] layout
    float* bmT = ws + 524288;        // 8192: routing keys [d][b]
    float* hws = ws + 532480;        // 524288: h = x + attn
    float* w1T = ws + 1056768;       // 16384
    float* w2T = ws + 1073152;       // 16384
    float* w3T = ws + 1089536;       // 16384

    k_prep<<<dim3(176), dim3(256), 0, stream>>>(x, pos, n1w, w1, w2, w3,
                                                A2, bmT, w1T, w2T, w3T);
    k_attn<<<dim3(4096), dim3(256), 0, stream>>>(x, A2, bmT, hws);
    k_mlp<<<dim3(256), dim3(256), 0, stream>>>(hws, n2w, w1T, b1, w2T, b2,
                                               w3T, b3, outp);
}

// Round 2
// 130.089 us; speedup vs baseline: 1.0004x; 1.0004x over previous
//
#include <hip/hip_runtime.h>
#include <math.h>

#define NPTS 8192
#define NB   128
#define EPS  1.1920929e-07f

__device__ __forceinline__ float rdlane(float v, int l) {
    return __int_as_float(__builtin_amdgcn_readlane(__float_as_int(v), l));
}

// ---------------------------------------------------------------------------
// K1: per-ball prep:  a = rmsnorm(x)*n1w + (pos - ball_mean(pos))
//     A2[b][h][m][e] (each (b,h) slice contiguous 2KB)
//     bm2[h][b][e]   routing keys (per-lane float4-loadable)
//     blocks >= NB pack MLP weights: w12 (w1/w2 interleaved), w3P (k-paired).
// ---------------------------------------------------------------------------
__global__ __launch_bounds__(256) void k_prep(
    const float* __restrict__ x, const float* __restrict__ pos,
    const float* __restrict__ n1w,
    const float* __restrict__ w1, const float* __restrict__ w2,
    const float* __restrict__ w3,
    float* __restrict__ A2, float* __restrict__ bm2,
    float* __restrict__ w12, float* __restrict__ w3P)
{
    int t = threadIdx.x;
    int blk = blockIdx.x;
    if (blk >= NB) {
        int base = (blk - NB) * 1024 + t * 4;
        #pragma unroll
        for (int c = 0; c < 4; ++c) {
            int idx = base + c;
            if (idx < 32768) {
                // w12[e*512 + u*128 + l*2 + s] = (s?w2:w1)[(u*64+l)*64 + e]
                int s = idx & 1, l = (idx >> 1) & 63, u = (idx >> 7) & 3, e = idx >> 9;
                w12[idx] = (s ? w2 : w1)[(u * 64 + l) * 64 + e];
            } else {
                // w3P[kp*128 + l*2 + s] = w3[l*256 + kp*2 + s]
                int o = idx - 32768;
                int s = o & 1, l = (o >> 1) & 63, kp = o >> 7;
                w3P[o] = w3[l * 256 + kp * 2 + s];
            }
        }
        return;
    }
    __shared__ float xs[64 * 68];
    __shared__ float ps[64 * 68];
    __shared__ float red[256], red2[256];
    __shared__ float pm[64], rs[64], nw[64];

    const float* xb = x + blk * 4096;
    const float* pb = pos + blk * 4096;
    if (t < 64) nw[t] = n1w[t];
    #pragma unroll
    for (int it = 0; it < 4; ++it) {
        int o4 = t + it * 256;
        int row = o4 >> 4, col = (o4 & 15) * 4;
        float4 xv = ((const float4*)xb)[o4];
        float4 pv = ((const float4*)pb)[o4];
        *(float4*)&xs[row * 68 + col] = xv;
        *(float4*)&ps[row * 68 + col] = pv;
    }
    __syncthreads();
    {
        int mg = t >> 6, d = t & 63;
        float s = 0.f;
        #pragma unroll
        for (int p = 0; p < 16; ++p) s += ps[(mg * 16 + p) * 68 + d];
        red[t] = s;
        int m = t >> 2, q = t & 3;
        float ss = 0.f;
        #pragma unroll
        for (int j = 0; j < 16; ++j) { float v = xs[m * 68 + q * 16 + j]; ss += v * v; }
        red2[t] = ss;
    }
    __syncthreads();
    if (t < 64) {
        pm[t] = (red[t] + red[t + 64] + red[t + 128] + red[t + 192]) * (1.0f / 64.0f);
        float s = red2[t * 4] + red2[t * 4 + 1] + red2[t * 4 + 2] + red2[t * 4 + 3];
        rs[t] = 1.0f / sqrtf(s * (1.0f / 64.0f) + EPS);
    }
    __syncthreads();
    {
        int m = t >> 2, q = t & 3;
        float sc = rs[m];
        #pragma unroll
        for (int j = 0; j < 16; ++j) {
            int d = q * 16 + j;
            int a = m * 68 + d;
            xs[a] = xs[a] * sc * nw[d] + (ps[a] - pm[d]);
        }
    }
    __syncthreads();
    {
        int mg = t >> 6, d = t & 63;
        float s = 0.f;
        #pragma unroll
        for (int p = 0; p < 16; ++p) s += xs[(mg * 16 + p) * 68 + d];
        red[t] = s;
        float* a2b = A2 + blk * 4096;
        #pragma unroll
        for (int it = 0; it < 16; ++it) {
            int o = t + it * 256;              // o = h*512 + m*8 + e
            int e = o & 7, m = (o >> 3) & 63, hh = o >> 9;
            a2b[o] = xs[m * 68 + hh * 8 + e];
        }
    }
    __syncthreads();
    if (t < 64) {
        float s = red[t] + red[t + 64] + red[t + 128] + red[t + 192];
        // bm2[h][b][e], h=t>>3, e=t&7
        bm2[(t >> 3) * 1024 + blk * 8 + (t & 7)] = s * (1.0f / 64.0f);
    }
}

// ---------------------------------------------------------------------------
// K2: routing (top-2, exact jax tie semantics) + attention + residual.
// 16 lanes per (point,head); K-data held in registers across both passes.
// ---------------------------------------------------------------------------
__global__ __launch_bounds__(256) void k_attn(
    const float* __restrict__ x, const float* __restrict__ A2,
    const float* __restrict__ bm2, float* __restrict__ hws)
{
    int h = blockIdx.x >> 9;
    int i = ((blockIdx.x & 511) << 4) + (threadIdx.x >> 4);
    int lane = threadIdx.x & 15;
    int bi = i >> 6, mi = i & 63;

    const float* qp = A2 + ((bi * 8 + h) * 64 + mi) * 8;
    float4 qa = ((const float4*)qp)[0];
    float4 qb = ((const float4*)qp)[1];

    // ---- routing: top-2 over 128 ball-mean keys (float4 loads) ----
    const float* bmh = bm2 + h * 1024;
    float bv0 = -3.4e38f, bv1 = -3.4e38f;
    int ix0 = 0, ix1 = 0;
    #pragma unroll
    for (int j = 0; j < 8; ++j) {
        int b = lane + j * 16;
        float4 f0 = ((const float4*)(bmh + b * 8))[0];
        float4 f1 = ((const float4*)(bmh + b * 8))[1];
        float lg = qa.x*f0.x + qa.y*f0.y + qa.z*f0.z + qa.w*f0.w
                 + qb.x*f1.x + qb.y*f1.y + qb.z*f1.z + qb.w*f1.w;
        if (lg > bv0)      { bv1 = bv0; ix1 = ix0; bv0 = lg; ix0 = b; }
        else if (lg > bv1) { bv1 = lg; ix1 = b; }
    }
    #pragma unroll
    for (int st = 1; st < 16; st <<= 1) {
        float ov0 = __shfl_xor(bv0, st); int oi0 = __shfl_xor(ix0, st);
        float ov1 = __shfl_xor(bv1, st); int oi1 = __shfl_xor(ix1, st);
        bool aw = (bv0 > ov0) || (bv0 == ov0 && ix0 < oi0);
        if (aw) {
            if ((ov0 > bv1) || (ov0 == bv1 && oi0 < ix1)) { bv1 = ov0; ix1 = oi0; }
        } else {
            if ((bv0 > ov1) || (bv0 == ov1 && ix0 < oi1)) { bv1 = bv0; ix1 = ix0; }
            else                                          { bv1 = ov1; ix1 = oi1; }
            bv0 = ov0; ix0 = oi0;
        }
    }

    // ---- load both balls' K-slices into registers, compute scores ----
    const float* k0 = A2 + (ix0 * 8 + h) * 512;
    const float* k1 = A2 + (ix1 * 8 + h) * 512;
    const float SC = 0.35355339059327373f;         // EH^-0.5
    float4 k0a[4], k0b[4], k1a[4], k1b[4];
    float s0[4], s1[4];
    float mx = -3.4e38f;
    #pragma unroll
    for (int jj = 0; jj < 4; ++jj) {
        int m = lane + jj * 16;
        k0a[jj] = ((const float4*)(k0 + m * 8))[0];
        k0b[jj] = ((const float4*)(k0 + m * 8))[1];
        k1a[jj] = ((const float4*)(k1 + m * 8))[0];
        k1b[jj] = ((const float4*)(k1 + m * 8))[1];
        float d0 = qa.x*k0a[jj].x + qa.y*k0a[jj].y + qa.z*k0a[jj].z + qa.w*k0a[jj].w
                 + qb.x*k0b[jj].x + qb.y*k0b[jj].y + qb.z*k0b[jj].z + qb.w*k0b[jj].w;
        s0[jj] = d0 * SC;
        float d1 = qa.x*k1a[jj].x + qa.y*k1a[jj].y + qa.z*k1a[jj].z + qa.w*k1a[jj].w
                 + qb.x*k1b[jj].x + qb.y*k1b[jj].y + qb.z*k1b[jj].z + qb.w*k1b[jj].w;
        s1[jj] = d1 * SC;
        mx = fmaxf(mx, fmaxf(s0[jj], s1[jj]));
    }
    #pragma unroll
    for (int st = 1; st < 16; st <<= 1) mx = fmaxf(mx, __shfl_xor(mx, st));
    float sum = 0.f;
    #pragma unroll
    for (int jj = 0; jj < 4; ++jj) {
        s0[jj] = expf(s0[jj] - mx); sum += s0[jj];
        s1[jj] = expf(s1[jj] - mx); sum += s1[jj];
    }
    #pragma unroll
    for (int st = 1; st < 16; st <<= 1) sum += __shfl_xor(sum, st);
    float inv = 1.0f / sum;

    float acc[8] = {0,0,0,0,0,0,0,0};
    #pragma unroll
    for (int jj = 0; jj < 4; ++jj) {
        float p = s0[jj] * inv;
        acc[0] += p*k0a[jj].x; acc[1] += p*k0a[jj].y; acc[2] += p*k0a[jj].z; acc[3] += p*k0a[jj].w;
        acc[4] += p*k0b[jj].x; acc[5] += p*k0b[jj].y; acc[6] += p*k0b[jj].z; acc[7] += p*k0b[jj].w;
        float p2 = s1[jj] * inv;
        acc[0] += p2*k1a[jj].x; acc[1] += p2*k1a[jj].y; acc[2] += p2*k1a[jj].z; acc[3] += p2*k1a[jj].w;
        acc[4] += p2*k1b[jj].x; acc[5] += p2*k1b[jj].y; acc[6] += p2*k1b[jj].z; acc[7] += p2*k1b[jj].w;
    }
    #pragma unroll
    for (int st = 1; st < 16; st <<= 1) {
        #pragma unroll
        for (int e = 0; e < 8; ++e) acc[e] += __shfl_xor(acc[e], st);
    }
    if (lane < 8) {
        float v = acc[0];
        #pragma unroll
        for (int e = 1; e < 8; ++e) if (lane == e) v = acc[e];
        int off = i * 64 + h * 8 + lane;
        hws[off] = x[off] + v;
    }
}

// ---------------------------------------------------------------------------
// K3: rmsnorm + SwiGLU + residual. 4 rows/wave (2048 waves = 2/SIMD),
// float2-packed weights, readlane activation broadcast, LDS-free.
// ---------------------------------------------------------------------------
__global__ __launch_bounds__(256) void k_mlp(
    const float* __restrict__ hws, const float* __restrict__ n2w,
    const float* __restrict__ w12, const float* __restrict__ b1,
    const float* __restrict__ b2,  const float* __restrict__ w3P,
    const float* __restrict__ b3,  float* __restrict__ out)
{
    int lane = threadIdx.x & 63;
    int wv = blockIdx.x * 4 + (threadIdx.x >> 6);
    int r0 = wv * 4;

    const float2* w12v = (const float2*)w12;
    const float2* w3v  = (const float2*)w3P;

    float hreg[4], hn[4];
    float nw = n2w[lane];
    #pragma unroll
    for (int r = 0; r < 4; ++r) hreg[r] = hws[(r0 + r) * 64 + lane];
    #pragma unroll
    for (int r = 0; r < 4; ++r) {
        float s = hreg[r] * hreg[r];
        #pragma unroll
        for (int st = 1; st < 64; st <<= 1) s += __shfl_xor(s, st);
        float sc = 1.0f / sqrtf(s * (1.0f / 64.0f) + EPS);
        hn[r] = hreg[r] * sc * nw;
    }

    float a1[16], a2[16];                          // [u*4+r]
    #pragma unroll
    for (int z = 0; z < 16; ++z) { a1[z] = 0.f; a2[z] = 0.f; }
    #pragma unroll 8
    for (int e = 0; e < 64; ++e) {
        float2 wv0 = w12v[e * 256 + lane];
        float2 wv1 = w12v[e * 256 + 64 + lane];
        float2 wv2 = w12v[e * 256 + 128 + lane];
        float2 wv3 = w12v[e * 256 + 192 + lane];
        #pragma unroll
        for (int r = 0; r < 4; ++r) {
            float hb = rdlane(hn[r], e);
            a1[r]      = fmaf(hb, wv0.x, a1[r]);      a2[r]      = fmaf(hb, wv0.y, a2[r]);
            a1[4 + r]  = fmaf(hb, wv1.x, a1[4 + r]);  a2[4 + r]  = fmaf(hb, wv1.y, a2[4 + r]);
            a1[8 + r]  = fmaf(hb, wv2.x, a1[8 + r]);  a2[8 + r]  = fmaf(hb, wv2.y, a2[8 + r]);
            a1[12 + r] = fmaf(hb, wv3.x, a1[12 + r]); a2[12 + r] = fmaf(hb, wv3.y, a2[12 + r]);
        }
    }

    float hid[16];
    #pragma unroll
    for (int u = 0; u < 4; ++u) {
        float bb1 = b1[u * 64 + lane], bb2 = b2[u * 64 + lane];
        #pragma unroll
        for (int r = 0; r < 4; ++r) {
            float z = a1[u * 4 + r] + bb1;
            float g = z / (1.0f + expf(-z));       // silu
            hid[u * 4 + r] = (a2[u * 4 + r] + bb2) * g;
        }
    }

    float acc[4] = {0,0,0,0};
    #pragma unroll
    for (int u = 0; u < 4; ++u) {
        #pragma unroll 8
        for (int kp = 0; kp < 32; ++kp) {
            float2 w = w3v[(u * 32 + kp) * 64 + lane];
            #pragma unroll
            for (int r = 0; r < 4; ++r) {
                float h0 = rdlane(hid[u * 4 + r], kp * 2);
                float h1 = rdlane(hid[u * 4 + r], kp * 2 + 1);
                acc[r] = fmaf(h0, w.x, acc[r]);
                acc[r] = fmaf(h1, w.y, acc[r]);
            }
        }
    }
    float b3vv = b3[lane];
    #pragma unroll
    for (int r = 0; r < 4; ++r)
        out[(r0 + r) * 64 + lane] = hreg[r] + acc[r] + b3vv;
}

// ---------------------------------------------------------------------------
extern "C" void kernel_launch(void* const* d_in, const int* in_sizes, int n_in,
                              void* d_out, int out_size, void* d_ws, size_t ws_size,
                              hipStream_t stream)
{
    const float* x   = (const float*)d_in[0];
    const float* pos = (const float*)d_in[1];
    const float* n1w = (const float*)d_in[2];
    const float* n2w = (const float*)d_in[3];
    const float* w1  = (const float*)d_in[4];
    const float* b1  = (const float*)d_in[5];
    const float* w2  = (const float*)d_in[6];
    const float* b2  = (const float*)d_in[7];
    const float* w3  = (const float*)d_in[8];
    const float* b3  = (const float*)d_in[9];
    float* outp = (float*)d_out;
    float* ws = (float*)d_ws;

    float* A2  = ws;                 // 524288 floats
    float* bm2 = ws + 524288;        // 8192: routing keys [h][b][e]
    float* hws = ws + 532480;        // 524288
    float* w12 = ws + 1056768;       // 32768: w1/w2 interleaved, [e][u][l][2]
    float* w3P = ws + 1089536;       // 16384: [kp][l][2]

    k_prep<<<dim3(176), dim3(256), 0, stream>>>(x, pos, n1w, w1, w2, w3,
                                                A2, bm2, w12, w3P);
    k_attn<<<dim3(4096), dim3(256), 0, stream>>>(x, A2, bm2, hws);
    k_mlp<<<dim3(512), dim3(256), 0, stream>>>(hws, n2w, w12, b1, b2,
                                               w3P, b3, outp);
}